// Round 6
// baseline (130.209 us; speedup 1.0000x reference)
//
#include <hip/hip_runtime.h>
#include <math.h>

// EdgeDetailAggregateLoss fused kernel for MI355X (gfx950).
// B=32, H=W=512. targets: NHWC C=2 f32; network_output: NHWC C=1 f32.
// Output: scalar focal-loss sum.
//
// Bit-exact simplification: fused mask = (0.6*e1 + 0.3*e2 + 0.1*e4 > 0.1f)
// with e* in {0,1}; 0.1f alone is never > 0.1f, so pos == e1 || e2 and the
// whole stride-4 branch is dead.
// Laplacian is identical for both target channels -> conv(t, lap) = lap(t0+t1).

#define B_ 32
#define H_ 512
#define W_ 512

constexpr int TY = 32;     // output tile rows per block
constexpr int TX = 64;     // output tile cols per block
constexpr int RRY = 37;    // staged rows [y0-2, y0+34]
constexpr int SSTR = 70;   // LDS row stride (even -> aligned pair writes; 70%32=6)

__global__ __launch_bounds__(256, 8) void edge_focal_kernel(
    const float* __restrict__ net,   // [B,H,W,1]
    const float* __restrict__ tgt,   // [B,H,W,2]
    double* __restrict__ partial)    // [gridDim.z*gridDim.y*gridDim.x]
{
    __shared__ float sT[RRY * SSTR];   // t0+t1 halo tile
    __shared__ float sB2[18 * 36];     // clipped stride-2 conv grid (<=18x34 used)
    __shared__ double sRed[4];

    const int tid = threadIdx.x;
    const int x0 = blockIdx.x * TX;
    const int y0 = blockIdx.y * TY;
    const int b  = blockIdx.z;

    const int lane = tid & 63;
    const int wv   = tid >> 6;
    const int py0  = wv * 8;
    const int gx   = x0 + lane;

    // ---- Early prefetch: issue the 8 net loads NOW so their HBM latency hides
    // under the LDS staging + conv phases (they have no dependence on LDS).
    const float* nb = net + (size_t)b * (H_ * W_);
    float p[8];
    #pragma unroll
    for (int i = 0; i < 8; ++i)
        p[i] = nb[(size_t)(y0 + py0 + i) * W_ + gx];

    // ---- Phase 1: stage s = t0+t1 over [y0-2,y0+34] x [x0-2,x0+66], zero-padded.
    // Column pairs c2=0..34 cover local cols 0..69 (col 69 is scratch).
    const float* tb = tgt + (size_t)b * (H_ * W_ * 2);
    const bool interior = (x0 >= 64) && (x0 <= 384) && (y0 >= 32) && (y0 <= 448);
    if (interior) {
        // 84/128 blocks: no bounds checks at all (block-uniform branch).
        for (int idx = tid; idx < RRY * 35; idx += 256) {
            int r  = idx / 35;
            int c2 = idx - r * 35;
            int gy  = y0 - 2 + r;
            int gxx = x0 - 2 + 2 * c2;
            const float4 q = *reinterpret_cast<const float4*>(tb + ((size_t)gy * W_ + gxx) * 2);
            sT[r * SSTR + 2 * c2]     = q.x + q.y;
            sT[r * SSTR + 2 * c2 + 1] = q.z + q.w;
        }
    } else {
        for (int idx = tid; idx < RRY * 35; idx += 256) {
            int r  = idx / 35;
            int c2 = idx - r * 35;
            int gy  = y0 - 2 + r;
            int gxx = x0 - 2 + 2 * c2;
            float v0 = 0.f, v1 = 0.f;
            if ((unsigned)gy < (unsigned)H_) {
                if (gxx >= 0 && gxx + 1 < W_) {
                    const float4 q = *reinterpret_cast<const float4*>(tb + ((size_t)gy * W_ + gxx) * 2);
                    v0 = q.x + q.y; v1 = q.z + q.w;
                } else {
                    if ((unsigned)gxx < (unsigned)W_) {
                        const float2 t2 = *reinterpret_cast<const float2*>(tb + ((size_t)gy * W_ + gxx) * 2);
                        v0 = t2.x + t2.y;
                    }
                    if ((unsigned)(gxx + 1) < (unsigned)W_) {
                        const float2 t2 = *reinterpret_cast<const float2*>(tb + ((size_t)gy * W_ + gxx + 1) * 2);
                        v1 = t2.x + t2.y;
                    }
                }
            }
            sT[r * SSTR + 2 * c2]     = v0;
            sT[r * SSTR + 2 * c2 + 1] = v1;
        }
    }
    __syncthreads();

    // align-corners interp scale, f64 divide then f32 cast (matches reference exactly)
    const float s2 = (float)(255.0 / 511.0);

    // ---- Phase 2: stride-2 conv grid (SAME pad lo=0,hi=1 -> window rows 2r..2r+2)
    const int r2lo = (int)((float)y0 * s2);
    const int c2lo = (int)((float)x0 * s2);
    const int r2hi = min((int)((float)(y0 + TY - 1) * s2) + 1, 255);
    const int c2hi = min((int)((float)(x0 + TX - 1) * s2) + 1, 255);
    const int n2r = r2hi - r2lo + 1, n2c = c2hi - c2lo + 1;

    for (int idx = tid; idx < 18 * 36; idx += 256) {
        int rr = idx / 36, cc = idx - rr * 36;
        if (rr < n2r && cc < n2c) {
            int ly = 2 * (r2lo + rr) - (y0 - 2);
            int lx = 2 * (c2lo + cc) - (x0 - 2);
            const float* q0 = &sT[ly * SSTR + lx];
            const float* q1 = q0 + SSTR;
            const float* q2 = q1 + SSTR;
            float s9 = q0[0] + q0[1] + q0[2] + q1[0] + q1[1] + q1[2] + q2[0] + q2[1] + q2[2];
            float cv = 9.f * q1[1] - s9;   // 8*center - neighbors
            sB2[idx] = fminf(fmaxf(cv, 0.f), 1.f);
        }
    }
    __syncthreads();

    // ---- Phase 4: per-pixel fuse + focal. Wave w owns rows [w*8, w*8+8).
    const int lx = lane + 2;

    // per-lane x-interp constants (hoisted)
    const float posx = (float)gx * s2;
    const int   j0   = (int)posx;
    const int   j1   = min(j0 + 1, 255);
    const float wx   = posx - (float)j0;
    const int   bc0  = j0 - c2lo, bc1 = j1 - c2lo;

    // rolling 3-wide row sums for the stride-1 conv
    const float* row = &sT[(py0 + 1) * SSTR + lx - 1];   // row ly-1 of first pixel
    float rs_m = row[0] + row[1] + row[2];
    row += SSTR;                                          // row ly
    float c_c = row[1];
    float rs_c = row[0] + c_c + row[2];

    float facc = 0.f;
    #pragma unroll
    for (int i = 0; i < 8; ++i) {
        const int py = py0 + i;
        const int gy = y0 + py;
        row = &sT[(py + 3) * SSTR + lx - 1];              // row ly+1
        const float n0 = row[0], n1 = row[1], n2 = row[2];
        const float rs_p = n0 + n1 + n2;

        const float cv1 = 9.f * c_c - (rs_m + rs_c + rs_p);
        const bool e1 = cv1 > 0.1f;

        // bilinear (align-corners) of clipped stride-2 grid (y-uniform terms -> SGPRs)
        const float posy = (float)gy * s2;
        const int   i0   = (int)posy;
        const int   i1   = min(i0 + 1, 255);
        const float wy   = posy - (float)i0;
        const int   a0   = i0 - r2lo, a1 = i1 - r2lo;
        const float v00 = sB2[a0 * 36 + bc0], v01 = sB2[a0 * 36 + bc1];
        const float v10 = sB2[a1 * 36 + bc0], v11 = sB2[a1 * 36 + bc1];
        const float ta  = v00 * (1.f - wy) + v10 * wy;
        const float tb2 = v01 * (1.f - wy) + v11 * wy;
        const float v2  = ta * (1.f - wx) + tb2 * wx;
        const bool e2 = v2 > 0.1f;

        const bool pos = e1 || e2;      // exact: 0.1*e4 alone can never exceed 0.1f
        const float pv = p[i];
        const float q  = pos ? pv : 1.f - pv;
        const float al = pos ? 0.25f : 0.75f;
        // native log: v_log_f32 (log2) * ln2 -- ~3 instrs vs ~30 for OCML logf.
        const float lg = fmaxf(__logf(q), -100.f);
        const float om = 1.f - q;
        facc += al * (-lg) * (om * om);

        rs_m = rs_c; rs_c = rs_p; c_c = n1;
    }

    // ---- Reduce: wave shuffle -> cross-wave LDS -> one partial per block
    #pragma unroll
    for (int off = 32; off > 0; off >>= 1)
        facc += __shfl_down(facc, off);
    if (lane == 0) sRed[wv] = (double)facc;
    __syncthreads();
    if (tid == 0) {
        partial[((size_t)blockIdx.z * gridDim.y + blockIdx.y) * gridDim.x + blockIdx.x] =
            sRed[0] + sRed[1] + sRed[2] + sRed[3];
    }
}

__global__ __launch_bounds__(1024) void reduce_partials(
    const double* __restrict__ partial, float* __restrict__ out, int n)
{
    __shared__ double sRed[16];
    double s = 0.0;
    for (int i = threadIdx.x; i < n; i += 1024) s += partial[i];
    #pragma unroll
    for (int off = 32; off > 0; off >>= 1)
        s += __shfl_down(s, off);
    if ((threadIdx.x & 63) == 0) sRed[threadIdx.x >> 6] = s;
    __syncthreads();
    if (threadIdx.x == 0) {
        double t = 0.0;
        #pragma unroll
        for (int k = 0; k < 16; ++k) t += sRed[k];
        out[0] = (float)t;
    }
}

extern "C" void kernel_launch(void* const* d_in, const int* in_sizes, int n_in,
                              void* d_out, int out_size, void* d_ws, size_t ws_size,
                              hipStream_t stream) {
    const float* net = (const float*)d_in[0];   // network_output
    const float* tgt = (const float*)d_in[1];   // targets
    // d_in[2] = laplacian, d_in[3] = fuse_kernel: fixed constants baked in.
    double* partial = (double*)d_ws;            // 4096 doubles = 32 KB scratch
    float* out = (float*)d_out;

    const dim3 grid(W_ / TX, H_ / TY, B_);      // 8 x 16 x 32 = 4096 blocks
    hipLaunchKernelGGL(edge_focal_kernel, grid, dim3(256), 0, stream, net, tgt, partial);
    hipLaunchKernelGGL(reduce_partials, dim3(1), dim3(1024), 0, stream,
                       partial, out, (int)(grid.x * grid.y * grid.z));
}

// Round 7
// 122.766 us; speedup vs baseline: 1.0606x; 1.0606x over previous
//
#include <hip/hip_runtime.h>
#include <math.h>

// EdgeDetailAggregateLoss fused kernel for MI355X (gfx950).
// B=32, H=W=512. targets: NHWC C=2 f32; network_output: NHWC C=1 f32.
// Output: scalar focal-loss sum.
//
// Bit-exact simplification: fused mask = (0.6*e1 + 0.3*e2 + 0.1*e4 > 0.1f)
// with e* in {0,1}; 0.1f alone is never > 0.1f, so pos == e1 || e2 and the
// whole stride-4 branch is dead.
// Laplacian is identical for both target channels -> conv(t, lap) = lap(t0+t1).
//
// R7 change: phase-1/phase-2 loops restructured to STATIC trip counts so the
// compiler fully unrolls and issues all global loads back-to-back (MLP=6/thread
// instead of 1). R6 showed the kernel is stall-bound, not VALU-bound.

#define B_ 32
#define H_ 512
#define W_ 512

constexpr int TY = 32;     // output tile rows per block
constexpr int TX = 64;     // output tile cols per block
constexpr int RRY = 37;    // staged rows [y0-2, y0+34]
constexpr int SSTR = 70;   // LDS row stride (even -> aligned pair writes; 70%32=6)
constexpr int NPAIR = RRY * 35;   // 1295 staged column-pairs

__global__ __launch_bounds__(256, 8) void edge_focal_kernel(
    const float* __restrict__ net,   // [B,H,W,1]
    const float* __restrict__ tgt,   // [B,H,W,2]
    double* __restrict__ partial)    // [gridDim.z*gridDim.y*gridDim.x]
{
    __shared__ float sT[RRY * SSTR];   // t0+t1 halo tile
    __shared__ float sB2[18 * 36];     // clipped stride-2 conv grid (<=18x34 used)
    __shared__ double sRed[4];

    const int tid = threadIdx.x;
    const int x0 = blockIdx.x * TX;
    const int y0 = blockIdx.y * TY;
    const int b  = blockIdx.z;

    const int lane = tid & 63;
    const int wv   = tid >> 6;
    const int py0  = wv * 8;
    const int gx   = x0 + lane;

    // ---- Phase 1a: issue ALL staging loads up-front (6 static slots/thread,
    // clamped addresses for OOB) -> 6 loads in flight per thread.
    const float* tb = tgt + (size_t)b * (H_ * W_ * 2);
    const bool interior = (x0 >= 64) && (x0 <= 384) && (y0 >= 32) && (y0 <= 448);
    float4 q[6];
    #pragma unroll
    for (int k = 0; k < 6; ++k) {
        const int idx = tid + k * 256;            // 0..1535 (>=NPAIR slots are dummies)
        const int r   = idx / 35;
        const int c2  = idx - r * 35;
        const int gy  = y0 - 2 + r;
        const int gxx = x0 - 2 + 2 * c2;
        const int gyc = min(max(gy, 0), H_ - 1);
        const int gxc = min(max(gxx, 0), W_ - 2); // float4 reads pixels (gxc, gxc+1)
        q[k] = *reinterpret_cast<const float4*>(tb + ((size_t)gyc * W_ + gxc) * 2);
    }

    // ---- net prefetch issued AFTER staging loads: the staging vmcnt wait
    // leaves these in flight; they're consumed only in phase 4.
    const float* nb = net + (size_t)b * (H_ * W_);
    float p[8];
    #pragma unroll
    for (int i = 0; i < 8; ++i)
        p[i] = nb[(size_t)(y0 + py0 + i) * W_ + gx];

    // ---- Phase 1b: masked LDS writes (OOB pixels -> 0).
    #pragma unroll
    for (int k = 0; k < 6; ++k) {
        const int idx = tid + k * 256;
        if (idx < NPAIR) {
            const int r  = idx / 35;
            const int c2 = idx - r * 35;
            float v0, v1;
            if (interior) {
                v0 = q[k].x + q[k].y;
                v1 = q[k].z + q[k].w;
            } else {
                const int gy  = y0 - 2 + r;
                const int gxx = x0 - 2 + 2 * c2;
                const bool oky = (unsigned)gy < (unsigned)H_;
                v0 = (oky && (unsigned)gxx       < (unsigned)W_) ? q[k].x + q[k].y : 0.f;
                v1 = (oky && (unsigned)(gxx + 1) < (unsigned)W_) ? q[k].z + q[k].w : 0.f;
            }
            sT[r * SSTR + 2 * c2]     = v0;
            sT[r * SSTR + 2 * c2 + 1] = v1;
        }
    }
    __syncthreads();

    // align-corners interp scale, f64 divide then f32 cast (matches reference exactly)
    const float s2 = (float)(255.0 / 511.0);

    // ---- Phase 2: stride-2 conv grid (SAME pad lo=0,hi=1 -> window rows 2r..2r+2).
    // Static 3-slot unroll (648 = 18*36 entries).
    const int r2lo = (int)((float)y0 * s2);
    const int c2lo = (int)((float)x0 * s2);
    const int r2hi = min((int)((float)(y0 + TY - 1) * s2) + 1, 255);
    const int c2hi = min((int)((float)(x0 + TX - 1) * s2) + 1, 255);
    const int n2r = r2hi - r2lo + 1, n2c = c2hi - c2lo + 1;

    #pragma unroll
    for (int k = 0; k < 3; ++k) {
        const int idx = tid + k * 256;
        if (idx < 18 * 36) {
            const int rr = idx / 36, cc = idx - rr * 36;
            if (rr < n2r && cc < n2c) {
                const int ly = 2 * (r2lo + rr) - (y0 - 2);
                const int lx = 2 * (c2lo + cc) - (x0 - 2);
                const float* q0 = &sT[ly * SSTR + lx];
                const float* q1 = q0 + SSTR;
                const float* q2 = q1 + SSTR;
                float s9 = q0[0] + q0[1] + q0[2] + q1[0] + q1[1] + q1[2] + q2[0] + q2[1] + q2[2];
                float cv = 9.f * q1[1] - s9;   // 8*center - neighbors
                sB2[idx] = fminf(fmaxf(cv, 0.f), 1.f);
            }
        }
    }
    __syncthreads();

    // ---- Phase 4: per-pixel fuse + focal. Wave w owns rows [w*8, w*8+8).
    const int lx = lane + 2;

    // per-lane x-interp constants (hoisted)
    const float posx = (float)gx * s2;
    const int   j0   = (int)posx;
    const int   j1   = min(j0 + 1, 255);
    const float wx   = posx - (float)j0;
    const int   bc0  = j0 - c2lo;
    const bool  xclamp = (j1 == j0);          // only possible at gx == 511

    // rolling 3-wide row sums for the stride-1 conv
    const float* row = &sT[(py0 + 1) * SSTR + lx - 1];   // row ly-1 of first pixel
    float rs_m = row[0] + row[1] + row[2];
    row += SSTR;                                          // row ly
    float c_c = row[1];
    float rs_c = row[0] + c_c + row[2];

    float facc = 0.f;
    #pragma unroll
    for (int i = 0; i < 8; ++i) {
        const int py = py0 + i;
        const int gy = y0 + py;
        row = &sT[(py + 3) * SSTR + lx - 1];              // row ly+1
        const float n0 = row[0], n1 = row[1], n2 = row[2];
        const float rs_p = n0 + n1 + n2;

        const float cv1 = 9.f * c_c - (rs_m + rs_c + rs_p);
        const bool e1 = cv1 > 0.1f;

        // bilinear (align-corners) of clipped stride-2 grid.
        // Read [bc0],[bc0+1] (adjacent -> ds_read2_b32) and select for the
        // j1==j0 clamp case (gx==511 only). sB2 row is 36 wide, bc0<=34 -> safe.
        const float posy = (float)gy * s2;
        const int   i0   = (int)posy;
        const int   i1   = min(i0 + 1, 255);
        const float wy   = posy - (float)i0;
        const int   a0   = i0 - r2lo, a1 = i1 - r2lo;
        const float v00 = sB2[a0 * 36 + bc0];
        const float v01r = sB2[a0 * 36 + bc0 + 1];
        const float v10 = sB2[a1 * 36 + bc0];
        const float v11r = sB2[a1 * 36 + bc0 + 1];
        const float v01 = xclamp ? v00 : v01r;
        const float v11 = xclamp ? v10 : v11r;
        const float ta  = v00 * (1.f - wy) + v10 * wy;
        const float tb2 = v01 * (1.f - wy) + v11 * wy;
        const float v2  = ta * (1.f - wx) + tb2 * wx;
        const bool e2 = v2 > 0.1f;

        const bool pos = e1 || e2;      // exact: 0.1*e4 alone can never exceed 0.1f
        const float pv = p[i];
        const float qv = pos ? pv : 1.f - pv;
        const float al = pos ? 0.25f : 0.75f;
        // native log: v_log_f32 (log2) * ln2 -- ~3 instrs vs ~30 for OCML logf.
        const float lg = fmaxf(__logf(qv), -100.f);
        const float om = 1.f - qv;
        facc += al * (-lg) * (om * om);

        rs_m = rs_c; rs_c = rs_p; c_c = n1;
    }

    // ---- Reduce: wave shuffle -> cross-wave LDS -> one partial per block
    #pragma unroll
    for (int off = 32; off > 0; off >>= 1)
        facc += __shfl_down(facc, off);
    if (lane == 0) sRed[wv] = (double)facc;
    __syncthreads();
    if (tid == 0) {
        partial[((size_t)blockIdx.z * gridDim.y + blockIdx.y) * gridDim.x + blockIdx.x] =
            sRed[0] + sRed[1] + sRed[2] + sRed[3];
    }
}

__global__ __launch_bounds__(1024) void reduce_partials(
    const double* __restrict__ partial, float* __restrict__ out, int n)
{
    __shared__ double sRed[16];
    double s = 0.0;
    for (int i = threadIdx.x; i < n; i += 1024) s += partial[i];
    #pragma unroll
    for (int off = 32; off > 0; off >>= 1)
        s += __shfl_down(s, off);
    if ((threadIdx.x & 63) == 0) sRed[threadIdx.x >> 6] = s;
    __syncthreads();
    if (threadIdx.x == 0) {
        double t = 0.0;
        #pragma unroll
        for (int k = 0; k < 16; ++k) t += sRed[k];
        out[0] = (float)t;
    }
}

extern "C" void kernel_launch(void* const* d_in, const int* in_sizes, int n_in,
                              void* d_out, int out_size, void* d_ws, size_t ws_size,
                              hipStream_t stream) {
    const float* net = (const float*)d_in[0];   // network_output
    const float* tgt = (const float*)d_in[1];   // targets
    // d_in[2] = laplacian, d_in[3] = fuse_kernel: fixed constants baked in.
    double* partial = (double*)d_ws;            // 4096 doubles = 32 KB scratch
    float* out = (float*)d_out;

    const dim3 grid(W_ / TX, H_ / TY, B_);      // 8 x 16 x 32 = 4096 blocks
    hipLaunchKernelGGL(edge_focal_kernel, grid, dim3(256), 0, stream, net, tgt, partial);
    hipLaunchKernelGGL(reduce_partials, dim3(1), dim3(1024), 0, stream,
                       partial, out, (int)(grid.x * grid.y * grid.z));
}

// Round 9
// 122.408 us; speedup vs baseline: 1.0637x; 1.0029x over previous
//
#include <hip/hip_runtime.h>
#include <math.h>

// EdgeDetailAggregateLoss fused kernel for MI355X (gfx950).
// B=32, H=W=512. targets: NHWC C=2 f32; network_output: NHWC C=1 f32.
// Output: scalar focal-loss sum.
//
// Bit-exact simplification: fused mask = (0.6*e1 + 0.3*e2 + 0.1*e4 > 0.1f)
// with e* in {0,1}; 0.1f alone is never > 0.1f, so pos == e1 || e2 and the
// whole stride-4 branch is dead.
// Laplacian is identical for both target channels -> conv(t, lap) = lap(t0+t1).
//
// R8: 2 px/lane (TX=128,TY=16), deinterleaved LDS halo (even cols sTe, odd sTo)
// so phase-4 conv reads are lane-stride-1 (no 4-way bank conflicts) and the two
// pixels share conv window values and y-interp lerps. All f32 expression orders
// kept identical to R7 (absmax protection).

#define B_ 32
#define H_ 512
#define W_ 512

constexpr int TY = 16;      // output tile rows
constexpr int TX = 128;     // output tile cols
constexpr int RRY = 21;     // staged rows [y0-2, y0+18]
constexpr int HSTR = 68;    // half-array row stride (67 col-pairs used)
constexpr int NPAIR = RRY * 67;   // 1407 staged column-pairs
constexpr int B2STR = 67;   // sB2 row stride (<=10 x <=66 used)

__global__ __launch_bounds__(256, 8) void edge_focal_kernel(
    const float* __restrict__ net,   // [B,H,W,1]
    const float* __restrict__ tgt,   // [B,H,W,2]
    double* __restrict__ partial)    // [4096]
{
    __shared__ float sTe[RRY * HSTR];   // even local cols: pair c -> local col 2c
    __shared__ float sTo[RRY * HSTR];   // odd  local cols: pair c -> local col 2c+1
    __shared__ float sB2[10 * B2STR];   // clipped stride-2 conv grid
    __shared__ double sRed[4];

    const int tid = threadIdx.x;
    const int x0 = blockIdx.x * TX;
    const int y0 = blockIdx.y * TY;
    const int b  = blockIdx.z;

    const int lane = tid & 63;
    const int wv   = tid >> 6;
    const int py0  = wv * 4;            // wave owns output rows [py0, py0+4)
    const int gx0  = x0 + 2 * lane;     // lane owns cols gx0, gx0+1

    // ---- Phase 1a: issue ALL staging loads up-front (6 static slots, clamped).
    const float* tb = tgt + (size_t)b * (H_ * W_ * 2);
    const bool interior = (x0 >= 128) && (x0 <= 256) && (y0 >= 16) && (y0 <= 480);
    float4 q[6];
    #pragma unroll
    for (int k = 0; k < 6; ++k) {
        const int idx = tid + k * 256;            // 0..1535 (>=NPAIR are dummies)
        const int r   = idx / 67;
        const int c2  = idx - r * 67;
        const int gy  = y0 - 2 + r;
        const int gxx = x0 - 2 + 2 * c2;
        const int gyc = min(max(gy, 0), H_ - 1);
        const int gxc = min(max(gxx, 0), W_ - 2); // float4 reads pixels (gxc, gxc+1)
        q[k] = *reinterpret_cast<const float4*>(tb + ((size_t)gyc * W_ + gxc) * 2);
    }

    // ---- net prefetch (float2 = both px), in flight until phase 4.
    const float* nb = net + (size_t)b * (H_ * W_);
    float2 pv[4];
    #pragma unroll
    for (int i = 0; i < 4; ++i)
        pv[i] = *reinterpret_cast<const float2*>(nb + (size_t)(y0 + py0 + i) * W_ + gx0);

    // ---- Phase 1b: masked deinterleaved LDS writes (OOB -> 0).
    #pragma unroll
    for (int k = 0; k < 6; ++k) {
        const int idx = tid + k * 256;
        if (idx < NPAIR) {
            const int r  = idx / 67;
            const int c2 = idx - r * 67;
            float v0, v1;
            if (interior) {
                v0 = q[k].x + q[k].y;
                v1 = q[k].z + q[k].w;
            } else {
                const int gy  = y0 - 2 + r;
                const int gxx = x0 - 2 + 2 * c2;
                const bool oky = (unsigned)gy < (unsigned)H_;
                v0 = (oky && (unsigned)gxx       < (unsigned)W_) ? q[k].x + q[k].y : 0.f;
                v1 = (oky && (unsigned)(gxx + 1) < (unsigned)W_) ? q[k].z + q[k].w : 0.f;
            }
            sTe[r * HSTR + c2] = v0;
            sTo[r * HSTR + c2] = v1;
        }
    }
    __syncthreads();

    // align-corners interp scale, f64 divide then f32 cast (matches reference)
    const float s2 = (float)(255.0 / 511.0);

    // ---- Phase 2: stride-2 conv grid (SAME pad lo=0,hi=1 -> window rows 2r..2r+2).
    const int r2lo = (int)((float)y0 * s2);
    const int c2lo = (int)((float)x0 * s2);
    const int r2hi = min((int)((float)(y0 + TY - 1) * s2) + 1, 255);
    const int c2hi = min((int)((float)(x0 + TX - 1) * s2) + 1, 255);
    const int n2r = r2hi - r2lo + 1, n2c = c2hi - c2lo + 1;

    #pragma unroll
    for (int k = 0; k < 3; ++k) {
        const int idx = tid + k * 256;
        if (idx < 10 * B2STR) {
            const int rr = idx / B2STR, cc = idx - rr * B2STR;
            if (rr < n2r && cc < n2c) {
                const int ly = 2 * (r2lo + rr) - (y0 - 2);
                const int e  = (2 * (c2lo + cc) - x0 + 2) >> 1;  // even local col -> half idx
                const float* pe = &sTe[ly * HSTR + e];
                const float* po = &sTo[ly * HSTR + e];
                // 9-term sum, row-major left-assoc (same order as R7)
                float s9 = pe[0] + po[0] + pe[1]
                         + pe[HSTR] + po[HSTR] + pe[HSTR + 1]
                         + pe[2 * HSTR] + po[2 * HSTR] + pe[2 * HSTR + 1];
                float cv = 9.f * po[HSTR] - s9;
                sB2[idx] = fminf(fmaxf(cv, 0.f), 1.f);
            }
        }
    }
    __syncthreads();

    // ---- Phase 4: 2 px/lane, 4 rows, rolling conv row-sums.
    // x-interp constants for both px (hoisted)
    const float posx0 = (float)gx0 * s2;
    const int   j00   = (int)posx0;
    const float wx0   = posx0 - (float)j00;
    const float posx1 = (float)(gx0 + 1) * s2;
    const int   j01   = (int)posx1;
    const float wx1   = posx1 - (float)j01;
    const int   d     = j01 - j00;            // 0 or 1
    const int   bc    = j00 - c2lo;
    const bool  jc1   = (j01 == 255);         // px1 x-clamp (gx=511 only)
    const float omwx0 = 1.f - wx0, omwx1 = 1.f - wx1;

    // conv window cols for the pair: local 2L+1..2L+4
    //   f0 = sTo[L], f1 = sTe[L+1], f2 = sTo[L+1], f3 = sTe[L+2]
    const int eb = lane + 1;

    float f0, f1, f2, f3;
    #define RD4(lr) do { \
        const float* pe_ = &sTe[(lr) * HSTR + eb]; \
        const float* po_ = &sTo[(lr) * HSTR + lane]; \
        f0 = po_[0]; f1 = pe_[0]; f2 = po_[1]; f3 = pe_[1]; \
    } while (0)

    RD4(py0 + 1);                       // row above first output row
    float h0m = f0 + f1 + f2;
    float h1m = f1 + f2 + f3;
    RD4(py0 + 2);                       // first output row
    float h0c = f0 + f1 + f2;
    float h1c = f1 + f2 + f3;
    float c0c = f1, c1c = f2;

    float facc = 0.f;
    #pragma unroll
    for (int i = 0; i < 4; ++i) {
        const int py = py0 + i;
        const int gy = y0 + py;
        RD4(py + 3);                    // row below
        const float h0p = f0 + f1 + f2;
        const float h1p = f1 + f2 + f3;
        const float n_c0 = f1, n_c1 = f2;

        const float cv0 = 9.f * c0c - (h0m + h0c + h0p);
        const float cv1 = 9.f * c1c - (h1m + h1c + h1p);
        const bool e1_0 = cv0 > 0.1f;
        const bool e1_1 = cv1 > 0.1f;

        // shared y-interp (reference form: y-lerp first, then x-lerp)
        const float posy = (float)gy * s2;
        const int   i0   = (int)posy;
        const int   i1   = min(i0 + 1, 255);
        const float wy   = posy - (float)i0;
        const float omwy = 1.f - wy;
        const int   a0   = i0 - r2lo, a1 = i1 - r2lo;
        const float w00 = sB2[a0 * B2STR + bc], w01 = sB2[a0 * B2STR + bc + 1], w02 = sB2[a0 * B2STR + bc + 2];
        const float w10 = sB2[a1 * B2STR + bc], w11 = sB2[a1 * B2STR + bc + 1], w12 = sB2[a1 * B2STR + bc + 2];
        const float ta = w00 * omwy + w10 * wy;
        const float tb2 = w01 * omwy + w11 * wy;
        const float tc = w02 * omwy + w12 * wy;

        const float v2_0 = ta * omwx0 + tb2 * wx0;
        const bool e2_0 = v2_0 > 0.1f;
        const float lo1 = d ? tb2 : ta;
        const float hi1 = jc1 ? lo1 : (d ? tc : tb2);
        const float v2_1 = lo1 * omwx1 + hi1 * wx1;
        const bool e2_1 = v2_1 > 0.1f;

        // focal terms (pos == e1 || e2, exact)
        {
            const bool pos = e1_0 || e2_0;
            const float p  = pv[i].x;
            const float qv = pos ? p : 1.f - p;
            const float al = pos ? 0.25f : 0.75f;
            const float lg = fmaxf(__logf(qv), -100.f);
            const float om = 1.f - qv;
            facc += al * (-lg) * (om * om);
        }
        {
            const bool pos = e1_1 || e2_1;
            const float p  = pv[i].y;
            const float qv = pos ? p : 1.f - p;
            const float al = pos ? 0.25f : 0.75f;
            const float lg = fmaxf(__logf(qv), -100.f);
            const float om = 1.f - qv;
            facc += al * (-lg) * (om * om);
        }

        h0m = h0c; h0c = h0p; h1m = h1c; h1c = h1p; c0c = n_c0; c1c = n_c1;
    }
    #undef RD4

    // ---- Reduce: wave shuffle -> cross-wave LDS -> one partial per block
    #pragma unroll
    for (int off = 32; off > 0; off >>= 1)
        facc += __shfl_down(facc, off);
    if (lane == 0) sRed[wv] = (double)facc;
    __syncthreads();
    if (tid == 0) {
        partial[((size_t)blockIdx.z * gridDim.y + blockIdx.y) * gridDim.x + blockIdx.x] =
            sRed[0] + sRed[1] + sRed[2] + sRed[3];
    }
}

__global__ __launch_bounds__(1024) void reduce_partials(
    const double* __restrict__ partial, float* __restrict__ out, int n)
{
    __shared__ double sRed[16];
    double s = 0.0;
    for (int i = threadIdx.x; i < n; i += 1024) s += partial[i];
    #pragma unroll
    for (int off = 32; off > 0; off >>= 1)
        s += __shfl_down(s, off);
    if ((threadIdx.x & 63) == 0) sRed[threadIdx.x >> 6] = s;
    __syncthreads();
    if (threadIdx.x == 0) {
        double t = 0.0;
        #pragma unroll
        for (int k = 0; k < 16; ++k) t += sRed[k];
        out[0] = (float)t;
    }
}

extern "C" void kernel_launch(void* const* d_in, const int* in_sizes, int n_in,
                              void* d_out, int out_size, void* d_ws, size_t ws_size,
                              hipStream_t stream) {
    const float* net = (const float*)d_in[0];   // network_output
    const float* tgt = (const float*)d_in[1];   // targets
    // d_in[2] = laplacian, d_in[3] = fuse_kernel: fixed constants baked in.
    double* partial = (double*)d_ws;            // 4096 doubles = 32 KB scratch
    float* out = (float*)d_out;

    const dim3 grid(W_ / TX, H_ / TY, B_);      // 4 x 32 x 32 = 4096 blocks
    hipLaunchKernelGGL(edge_focal_kernel, grid, dim3(256), 0, stream, net, tgt, partial);
    hipLaunchKernelGGL(reduce_partials, dim3(1), dim3(1024), 0, stream,
                       partial, out, (int)(grid.x * grid.y * grid.z));
}